// Round 1
// baseline (31.489 us; speedup 1.0000x reference)
//
#include <hip/hip_runtime.h>
#include <math.h>

#define N_PTS 4096
#define FLOATS_PER_BATCH (N_PTS * 3)          // 12288
#define BLK 256
#define FLOATS_PER_THREAD (FLOATS_PER_BATCH / BLK)  // 48
#define STATS 17

__device__ inline double wave_reduce_sum(double v) {
    #pragma unroll
    for (int off = 32; off > 0; off >>= 1) v += __shfl_xor(v, off, 64);
    return v;
}

// Kernel 1: per-batch sufficient statistics.
// ws[b*17 + {0..2}] = sum pred, {3..5} = sum true, {6} = sum ||pred||^2,
// {7} = sum ||true||^2, {8..16} = sum pred_i * true_j (row-major 3x3)
__global__ __launch_bounds__(BLK) void kabsch_reduce(const float* __restrict__ pred,
                                                     const float* __restrict__ tru,
                                                     double* __restrict__ ws) {
    const int b = blockIdx.x;
    const int tid = threadIdx.x;
    const float4* p4 = reinterpret_cast<const float4*>(
        pred + (size_t)b * FLOATS_PER_BATCH + (size_t)tid * FLOATS_PER_THREAD);
    const float4* t4 = reinterpret_cast<const float4*>(
        tru + (size_t)b * FLOATS_PER_BATCH + (size_t)tid * FLOATS_PER_THREAD);

    double sp0 = 0, sp1 = 0, sp2 = 0, st0 = 0, st1 = 0, st2 = 0, spp = 0, stt = 0;
    double M00 = 0, M01 = 0, M02 = 0, M10 = 0, M11 = 0, M12 = 0, M20 = 0, M21 = 0, M22 = 0;

    #pragma unroll
    for (int k = 0; k < 4; ++k) {
        float4 a0 = p4[k * 3 + 0], a1 = p4[k * 3 + 1], a2 = p4[k * 3 + 2];
        float4 c0 = t4[k * 3 + 0], c1 = t4[k * 3 + 1], c2 = t4[k * 3 + 2];
        float pf[12] = {a0.x, a0.y, a0.z, a0.w, a1.x, a1.y, a1.z, a1.w, a2.x, a2.y, a2.z, a2.w};
        float tf[12] = {c0.x, c0.y, c0.z, c0.w, c1.x, c1.y, c1.z, c1.w, c2.x, c2.y, c2.z, c2.w};
        #pragma unroll
        for (int i = 0; i < 4; ++i) {
            double px = (double)pf[i * 3 + 0], py = (double)pf[i * 3 + 1], pz = (double)pf[i * 3 + 2];
            double tx = (double)tf[i * 3 + 0], ty = (double)tf[i * 3 + 1], tz = (double)tf[i * 3 + 2];
            sp0 += px; sp1 += py; sp2 += pz;
            st0 += tx; st1 += ty; st2 += tz;
            spp = fma(px, px, fma(py, py, fma(pz, pz, spp)));
            stt = fma(tx, tx, fma(ty, ty, fma(tz, tz, stt)));
            M00 = fma(px, tx, M00); M01 = fma(px, ty, M01); M02 = fma(px, tz, M02);
            M10 = fma(py, tx, M10); M11 = fma(py, ty, M11); M12 = fma(py, tz, M12);
            M20 = fma(pz, tx, M20); M21 = fma(pz, ty, M21); M22 = fma(pz, tz, M22);
        }
    }

    double vals[STATS] = {sp0, sp1, sp2, st0, st1, st2, spp, stt,
                          M00, M01, M02, M10, M11, M12, M20, M21, M22};
    __shared__ double red[BLK / 64][STATS];
    const int lane = tid & 63, wid = tid >> 6;
    #pragma unroll
    for (int i = 0; i < STATS; ++i) {
        double r = wave_reduce_sum(vals[i]);
        if (lane == 0) red[wid][i] = r;
    }
    __syncthreads();
    if (tid < STATS) {
        double t = 0;
        #pragma unroll
        for (int w = 0; w < BLK / 64; ++w) t += red[w][tid];
        ws[(size_t)b * STATS + tid] = t;
    }
}

// Kernel 2: per-batch 3x3 closed-form singular values + RMSD, mean over B.
__global__ __launch_bounds__(1024) void kabsch_finalize(const double* __restrict__ ws,
                                                        float* __restrict__ out, int B) {
    const int tid = threadIdx.x;
    double rmsd = 0.0;
    if (tid < B) {
        const double* w = ws + (size_t)tid * STATS;
        const double invN = 1.0 / (double)N_PTS;
        double sp[3] = {w[0], w[1], w[2]};
        double st[3] = {w[3], w[4], w[5]};
        double spp = w[6], stt = w[7];
        double A[3][3];
        #pragma unroll
        for (int i = 0; i < 3; ++i)
            #pragma unroll
            for (int j = 0; j < 3; ++j)
                A[i][j] = w[8 + i * 3 + j] - sp[i] * st[j] * invN;
        double Sp = spp - (sp[0] * sp[0] + sp[1] * sp[1] + sp[2] * sp[2]) * invN;
        double St = stt - (st[0] * st[0] + st[1] * st[1] + st[2] * st[2]) * invN;

        double detA = A[0][0] * (A[1][1] * A[2][2] - A[1][2] * A[2][1])
                    - A[0][1] * (A[1][0] * A[2][2] - A[1][2] * A[2][0])
                    + A[0][2] * (A[1][0] * A[2][1] - A[1][1] * A[2][0]);

        // G = A^T A (symmetric, PSD)
        double G00 = A[0][0]*A[0][0] + A[1][0]*A[1][0] + A[2][0]*A[2][0];
        double G11 = A[0][1]*A[0][1] + A[1][1]*A[1][1] + A[2][1]*A[2][1];
        double G22 = A[0][2]*A[0][2] + A[1][2]*A[1][2] + A[2][2]*A[2][2];
        double G01 = A[0][0]*A[0][1] + A[1][0]*A[1][1] + A[2][0]*A[2][1];
        double G02 = A[0][0]*A[0][2] + A[1][0]*A[1][2] + A[2][0]*A[2][2];
        double G12 = A[0][1]*A[0][2] + A[1][1]*A[1][2] + A[2][1]*A[2][2];

        // Closed-form symmetric 3x3 eigenvalues (descending e1 >= e2 >= e3).
        double q = (G00 + G11 + G22) / 3.0;
        double p1 = G01 * G01 + G02 * G02 + G12 * G12;
        double b00 = G00 - q, b11 = G11 - q, b22 = G22 - q;
        double p2 = b00 * b00 + b11 * b11 + b22 * b22 + 2.0 * p1;
        double p = sqrt(p2 / 6.0);
        double e1, e2, e3;
        if (p > 1e-300 + 1e-14 * fabs(q)) {
            double ip = 1.0 / p;
            double C00 = b00 * ip, C11 = b11 * ip, C22 = b22 * ip;
            double C01 = G01 * ip, C02 = G02 * ip, C12 = G12 * ip;
            double r = 0.5 * (C00 * (C11 * C22 - C12 * C12)
                            - C01 * (C01 * C22 - C12 * C02)
                            + C02 * (C01 * C12 - C11 * C02));
            r = fmin(1.0, fmax(-1.0, r));
            double phi = acos(r) / 3.0;
            e1 = q + 2.0 * p * cos(phi);
            e3 = q + 2.0 * p * cos(phi + 2.0943951023931953);  // + 2*pi/3
            e2 = 3.0 * q - e1 - e3;
        } else {
            e1 = e2 = e3 = q;
        }
        double s1 = sqrt(fmax(e1, 0.0));
        double s2 = sqrt(fmax(e2, 0.0));
        double s3 = sqrt(fmax(e3, 0.0));  // smallest singular value
        double d = (detA < 0.0) ? -1.0 : 1.0;
        double tr = s1 + s2 + d * s3;
        double msd = (Sp + St - 2.0 * tr) * invN;
        rmsd = sqrt(fmax(msd, 0.0));
    }

    rmsd = wave_reduce_sum(rmsd);
    __shared__ double red[16];
    const int lane = tid & 63, wid = tid >> 6;
    if (lane == 0) red[wid] = rmsd;
    __syncthreads();
    if (tid == 0) {
        double tot = 0.0;
        #pragma unroll
        for (int w = 0; w < 16; ++w) tot += red[w];
        out[0] = (float)(tot / (double)B);
    }
}

extern "C" void kernel_launch(void* const* d_in, const int* in_sizes, int n_in,
                              void* d_out, int out_size, void* d_ws, size_t ws_size,
                              hipStream_t stream) {
    const float* pred = (const float*)d_in[0];
    const float* tru  = (const float*)d_in[1];
    float* out = (float*)d_out;
    double* ws = (double*)d_ws;
    const int B = in_sizes[0] / FLOATS_PER_BATCH;  // 1024

    kabsch_reduce<<<dim3(B), dim3(BLK), 0, stream>>>(pred, tru, ws);
    kabsch_finalize<<<dim3(1), dim3(1024), 0, stream>>>(ws, out, B);
}